// Round 1
// baseline (2837.457 us; speedup 1.0000x reference)
//
#include <hip/hip_runtime.h>

typedef unsigned long long u64;
typedef unsigned int u32;

#define MQ 2048
#define ND 50000
#define DD 512

constexpr int BM = 128, BN = 128, KC = 16;
constexpr int QSTR = BM + 4;   // padded LDS stride (132)

__device__ __forceinline__ void insert10(u64 (&lst)[10], u64 key) {
  // lst sorted descending; caller guarantees key > lst[9]
  u64 cur = key;
#pragma unroll
  for (int p = 0; p < 10; ++p) {
    u64 a = lst[p];
    u64 mx = a > cur ? a : cur;
    cur    = a > cur ? cur : a;
    lst[p] = mx;
  }
}

// ---------------- kernel 1: squared norms of all rows ----------------
__global__ __launch_bounds__(256) void sqnorm_kernel(
    const float* __restrict__ Q, const float* __restrict__ R,
    float* __restrict__ rsq, float* __restrict__ qsq)
{
  int wid  = blockIdx.x * 4 + (threadIdx.x >> 6);
  int lane = threadIdx.x & 63;
  if (wid >= ND + MQ) return;
  const float* p = (wid < ND) ? (R + (size_t)wid * DD)
                              : (Q + (size_t)(wid - ND) * DD);
  float s = 0.f;
#pragma unroll
  for (int it = 0; it < 2; ++it) {
    float4 v = *reinterpret_cast<const float4*>(p + lane * 4 + it * 256);
    s += v.x * v.x + v.y * v.y + v.z * v.z + v.w * v.w;
  }
#pragma unroll
  for (int off = 32; off > 0; off >>= 1) s += __shfl_down(s, off, 64);
  if (lane == 0) {
    if (wid < ND) rsq[wid] = s;
    else          qsq[wid - ND] = s;
  }
}

// ------------- kernel 2: fused tiled GEMM-distance + per-chunk top-10 -------------
__global__ __launch_bounds__(256, 3) void knn_gemm_topk(
    const float* __restrict__ Q, const float* __restrict__ R,
    const float* __restrict__ qsq, const float* __restrict__ rsq,
    u64* __restrict__ cand, int chunkCols)
{
  __shared__ float Qs[KC][QSTR];
  __shared__ float Rs[KC][QSTR];
  __shared__ __align__(16) u32 DS[64 * BN];   // 32 KB: half-tile of dist keys

  const int t  = threadIdx.x;
  const int tx = t & 15;         // GEMM col group (8 cols)
  const int ty = t >> 4;         // GEMM row group (8 rows)
  const int qbase  = blockIdx.x * BM;
  const int cbase0 = blockIdx.y * chunkCols;

  u64 lst[10];
#pragma unroll
  for (int i = 0; i < 10; ++i) lst[i] = 0ull;

  const int tkrow  = t >> 1;        // local query row this thread tracks (0..127)
  const int tkhalf = tkrow >> 6;
  const int tkr    = tkrow & 63;
  const int tkc0   = (t & 1) * 64;  // which 64-col half of the subtile

  for (int s = 0; s * BN < chunkCols; ++s) {
    const int cbase = cbase0 + s * BN;
    if (cbase >= ND) break;

    float acc[8][8];
#pragma unroll
    for (int i = 0; i < 8; ++i)
#pragma unroll
      for (int j = 0; j < 8; ++j) acc[i][j] = 0.f;

    for (int k0 = 0; k0 < DD; k0 += KC) {
      // stage Q/R k-slices, transposed (k-major) into LDS
#pragma unroll
      for (int i2 = 0; i2 < 2; ++i2) {
        int idx = t + i2 * 256;
        int r  = idx >> 2;
        int c4 = (idx & 3) * 4;
        float4 qv = *reinterpret_cast<const float4*>(Q + (size_t)(qbase + r) * DD + k0 + c4);
        Qs[c4 + 0][r] = qv.x; Qs[c4 + 1][r] = qv.y;
        Qs[c4 + 2][r] = qv.z; Qs[c4 + 3][r] = qv.w;
        int rr = cbase + r; if (rr >= ND) rr = ND - 1;
        float4 rv = *reinterpret_cast<const float4*>(R + (size_t)rr * DD + k0 + c4);
        Rs[c4 + 0][r] = rv.x; Rs[c4 + 1][r] = rv.y;
        Rs[c4 + 2][r] = rv.z; Rs[c4 + 3][r] = rv.w;
      }
      __syncthreads();
#pragma unroll
      for (int kk = 0; kk < KC; ++kk) {
        float a[8], b[8];
        *reinterpret_cast<float4*>(&a[0]) = *reinterpret_cast<const float4*>(&Qs[kk][ty * 8]);
        *reinterpret_cast<float4*>(&a[4]) = *reinterpret_cast<const float4*>(&Qs[kk][ty * 8 + 4]);
        *reinterpret_cast<float4*>(&b[0]) = *reinterpret_cast<const float4*>(&Rs[kk][tx * 8]);
        *reinterpret_cast<float4*>(&b[4]) = *reinterpret_cast<const float4*>(&Rs[kk][tx * 8 + 4]);
#pragma unroll
        for (int i = 0; i < 8; ++i)
#pragma unroll
          for (int j = 0; j < 8; ++j) acc[i][j] = fmaf(a[i], b[j], acc[i][j]);
      }
      __syncthreads();
    }

    // distance keys -> LDS (two 64-row halves); stream into per-thread top-10
#pragma unroll
    for (int half = 0; half < 2; ++half) {
      if ((ty >> 3) == half) {
        const int rl = (ty & 7) * 8;
#pragma unroll
        for (int i = 0; i < 8; ++i) {
          const float qs = qsq[qbase + ty * 8 + i];
#pragma unroll
          for (int j = 0; j < 8; ++j) {
            const int col = cbase + tx * 8 + j;
            u32 kb = 0u;
            if (col < ND) {
              float d = qs + rsq[col] - 2.0f * acc[i][j];
              kb = __float_as_uint(d);
              // monotone transform: sign-aware order-preserving uint
              kb ^= (kb & 0x80000000u) ? 0xFFFFFFFFu : 0x80000000u;
            }
            DS[(rl + i) * BN + tx * 8 + j] = kb;
          }
        }
      }
      __syncthreads();
      if (tkhalf == half) {
#pragma unroll 4
        for (int cc = 0; cc < 64; ++cc) {
          const int c   = (cc + tkr) & 63;        // rotate start -> avoid 32-way bank conflict
          const u32 kb  = DS[tkr * BN + tkc0 + c];
          const int col = cbase + tkc0 + c;
          const u64 key = ((u64)kb << 16) | (u64)((col ^ 0xFFFF) & 0xFFFF);
          if (key > lst[9]) insert10(lst, key);
        }
      }
      __syncthreads();
    }
  }

  // merge the two half-row lists of each query row; write 10 candidates/row
  u64* L = reinterpret_cast<u64*>(DS);
#pragma unroll
  for (int i = 0; i < 10; ++i) L[t * 10 + i] = lst[i];
  __syncthreads();
  if (t < BM) {
    u64 best[10];
#pragma unroll
    for (int i = 0; i < 10; ++i) best[i] = L[(2 * t) * 10 + i];
#pragma unroll
    for (int i = 0; i < 10; ++i) {
      u64 key = L[(2 * t + 1) * 10 + i];
      if (key <= best[9]) break;   // lists sorted desc: rest can't qualify
      insert10(best, key);
    }
    const size_t base = (size_t)blockIdx.y * 10;
#pragma unroll
    for (int j = 0; j < 10; ++j)
      cand[(base + j) * MQ + qbase + t] = best[j];
  }
}

// ---------------- kernel 3: merge candidates, labels, mode ----------------
__global__ __launch_bounds__(256) void knn_finalize(
    const u64* __restrict__ cand, float* __restrict__ out, int nSlots)
{
  const int row = blockIdx.x * 256 + threadIdx.x;
  if (row >= MQ) return;
  u64 lst[10];
#pragma unroll
  for (int i = 0; i < 10; ++i) lst[i] = 0ull;
  for (int s2 = 0; s2 < nSlots; ++s2) {
    const u64 key = cand[(size_t)s2 * MQ + row];   // coalesced: stride-1 in row
    if (key > lst[9]) insert10(lst, key);
  }
  // labels = col/5000 ; mode with first-wins tie-break (matches argmax)
  int best = 0, bestc = 0;
#pragma unroll
  for (int cls = 0; cls < 10; ++cls) {
    int cnt = 0;
#pragma unroll
    for (int j = 0; j < 10; ++j) {
      const int col = ((int)(lst[j] & 0xFFFFull)) ^ 0xFFFF;
      cnt += (col / 5000 == cls) ? 1 : 0;
    }
    if (cnt > bestc) { bestc = cnt; best = cls; }
  }
  out[row] = (float)best;
}

extern "C" void kernel_launch(void* const* d_in, const int* in_sizes, int n_in,
                              void* d_out, int out_size, void* d_ws, size_t ws_size,
                              hipStream_t stream)
{
  const float* Q = (const float*)d_in[0];
  const float* R = (const float*)d_in[1];
  float* out = (float*)d_out;

  // workspace: [cand: NC*10*MQ u64][rsq: ND f32][qsq: MQ f32]; shrink NC if needed
  int NC = 49;
  const size_t perChunk  = (size_t)10 * MQ * sizeof(u64);
  const size_t fixedTail = (size_t)(ND + MQ) * sizeof(float);
  while (NC > 1 && (size_t)NC * perChunk + fixedTail > ws_size) --NC;
  int chunkCols = (((ND + NC - 1) / NC) + BN - 1) / BN * BN;
  NC = (ND + chunkCols - 1) / chunkCols;   // effective chunk count

  u64*   cand = (u64*)d_ws;
  float* rsq  = (float*)((char*)d_ws + (size_t)NC * perChunk);
  float* qsq  = rsq + ND;

  const int nrows = ND + MQ;
  sqnorm_kernel<<<(nrows + 3) / 4, 256, 0, stream>>>(Q, R, rsq, qsq);
  knn_gemm_topk<<<dim3(MQ / BM, NC), 256, 0, stream>>>(Q, R, qsq, rsq, cand, chunkCols);
  knn_finalize<<<MQ / 256, 256, 0, stream>>>(cand, out, NC * 10);
}

// Round 2
// 2585.196 us; speedup vs baseline: 1.0976x; 1.0976x over previous
//
#include <hip/hip_runtime.h>

typedef unsigned long long u64;
typedef unsigned int u32;

#define MQ 2048
#define ND 50000
#define DD 512

constexpr int BM = 128, BN = 128, KC = 16;
constexpr int QSTR = BM + 4;   // padded LDS stride for Q/R k-slices (132)
constexpr int DSTR = BN + 4;   // padded LDS stride for distance subtile

__device__ __forceinline__ void insert10(u64 (&lst)[10], u64 key) {
  // lst sorted descending; caller guarantees key > lst[9]
  u64 cur = key;
#pragma unroll
  for (int p = 0; p < 10; ++p) {
    u64 a = lst[p];
    u64 mx = a > cur ? a : cur;
    cur    = a > cur ? cur : a;
    lst[p] = mx;
  }
}

// ---------------- kernel 1: squared norms of all rows ----------------
__global__ __launch_bounds__(256) void sqnorm_kernel(
    const float* __restrict__ Q, const float* __restrict__ R,
    float* __restrict__ rsq, float* __restrict__ qsq)
{
  int wid  = blockIdx.x * 4 + (threadIdx.x >> 6);
  int lane = threadIdx.x & 63;
  if (wid >= ND + MQ) return;
  const float* p = (wid < ND) ? (R + (size_t)wid * DD)
                              : (Q + (size_t)(wid - ND) * DD);
  float s = 0.f;
#pragma unroll
  for (int it = 0; it < 2; ++it) {
    float4 v = *reinterpret_cast<const float4*>(p + lane * 4 + it * 256);
    s += v.x * v.x + v.y * v.y + v.z * v.z + v.w * v.w;
  }
#pragma unroll
  for (int off = 32; off > 0; off >>= 1) s += __shfl_down(s, off, 64);
  if (lane == 0) {
    if (wid < ND) rsq[wid] = s;
    else          qsq[wid - ND] = s;
  }
}

// ------------- kernel 2: fused tiled GEMM-distance + per-chunk top-10 -------------
// launch_bounds(256,2): VGPR cap 256 -> prevent the round-1 scratch spill of lst/acc.
__global__ __launch_bounds__(256, 2) void knn_gemm_topk(
    const float* __restrict__ Q, const float* __restrict__ R,
    const float* __restrict__ qsq, const float* __restrict__ rsq,
    u64* __restrict__ cand, int chunkCols)
{
  __shared__ float Qs[KC][QSTR];
  __shared__ float Rs[KC][QSTR];
  __shared__ __align__(16) u32 DS[64 * DSTR];   // 33 KB: half-tile of dist keys

  const int t  = threadIdx.x;
  const int tx = t & 15;         // GEMM col group
  const int ty = t >> 4;         // GEMM row group
  const int qbase  = blockIdx.x * BM;
  const int cbase0 = blockIdx.y * chunkCols;

  u64 lst[10];
#pragma unroll
  for (int i = 0; i < 10; ++i) lst[i] = 0ull;

  // top-k ownership: bit0 = half (row 0-63 vs 64-127), bits1-6 = row-in-half,
  // bit7 = 64-col segment
  const int tkhalf = t & 1;
  const int tkr    = (t >> 1) & 63;
  const int tkc0   = (t >> 7) * 64;

  for (int s = 0; s * BN < chunkCols; ++s) {
    const int cbase = cbase0 + s * BN;
    if (cbase >= ND) break;

    float acc[8][8];
#pragma unroll
    for (int i = 0; i < 8; ++i)
#pragma unroll
      for (int j = 0; j < 8; ++j) acc[i][j] = 0.f;

    for (int k0 = 0; k0 < DD; k0 += KC) {
      // stage Q/R k-slices, transposed (k-major) into LDS
#pragma unroll
      for (int i2 = 0; i2 < 2; ++i2) {
        int idx = t + i2 * 256;
        int r  = idx >> 2;
        int c4 = (idx & 3) * 4;
        float4 qv = *reinterpret_cast<const float4*>(Q + (size_t)(qbase + r) * DD + k0 + c4);
        Qs[c4 + 0][r] = qv.x; Qs[c4 + 1][r] = qv.y;
        Qs[c4 + 2][r] = qv.z; Qs[c4 + 3][r] = qv.w;
        int rr = cbase + r; if (rr >= ND) rr = ND - 1;
        float4 rv = *reinterpret_cast<const float4*>(R + (size_t)rr * DD + k0 + c4);
        Rs[c4 + 0][r] = rv.x; Rs[c4 + 1][r] = rv.y;
        Rs[c4 + 2][r] = rv.z; Rs[c4 + 3][r] = rv.w;
      }
      __syncthreads();
#pragma unroll
      for (int kk = 0; kk < KC; ++kk) {
        // split fragments (tx*4 and 64+tx*4): 2-way LDS conflict (free) vs 4-way before
        float a[8], b[8];
        *reinterpret_cast<float4*>(&a[0]) = *reinterpret_cast<const float4*>(&Qs[kk][ty * 4]);
        *reinterpret_cast<float4*>(&a[4]) = *reinterpret_cast<const float4*>(&Qs[kk][64 + ty * 4]);
        *reinterpret_cast<float4*>(&b[0]) = *reinterpret_cast<const float4*>(&Rs[kk][tx * 4]);
        *reinterpret_cast<float4*>(&b[4]) = *reinterpret_cast<const float4*>(&Rs[kk][64 + tx * 4]);
#pragma unroll
        for (int i = 0; i < 8; ++i)
#pragma unroll
          for (int j = 0; j < 8; ++j) acc[i][j] = fmaf(a[i], b[j], acc[i][j]);
      }
      __syncthreads();
    }

    // distance keys -> LDS (two 64-row halves); stream into per-thread top-10
#pragma unroll
    for (int h = 0; h < 2; ++h) {
#pragma unroll
      for (int i2 = 0; i2 < 4; ++i2) {
        const int rloc = ty * 4 + i2;                  // 0..63 within half
        const float qs = qsq[qbase + 64 * h + rloc];
#pragma unroll
        for (int j = 0; j < 8; ++j) {
          const int cloc = (j < 4) ? tx * 4 + j : 64 + tx * 4 + (j - 4);
          const int col  = cbase + cloc;
          u32 kb = 0u;
          if (col < ND) {
            float d = qs + rsq[col] - 2.0f * acc[h * 4 + i2][j];
            kb = __float_as_uint(d);
            kb ^= (kb & 0x80000000u) ? 0xFFFFFFFFu : 0x80000000u;  // order-preserving
          }
          DS[rloc * DSTR + cloc] = kb;
        }
      }
      __syncthreads();
      if (tkhalf == h) {
        for (int cc = 0; cc < 64; ++cc) {
          const int c   = (cc + tkr) & 63;        // rotate start -> spread banks
          const u32 kb  = DS[tkr * DSTR + tkc0 + c];
          const int col = cbase + tkc0 + c;
          const u64 key = ((u64)kb << 16) | (u64)((col ^ 0xFFFF) & 0xFFFF);
          if (key > lst[9]) insert10(lst, key);
        }
      }
      __syncthreads();
    }
  }

  // epilogue: merge the two col-segment lists of each query row; write 10/row
  u64* L = reinterpret_cast<u64*>(DS);
#pragma unroll
  for (int i = 0; i < 10; ++i) L[t * 10 + i] = lst[i];
  __syncthreads();
  if (t < BM) {
    // global row qbase + t  ->  owner threads: ((t&63)<<1)|(t>>6)  and  +128
    const int t1 = ((t & 63) << 1) | (t >> 6);
    const int t2 = t1 | 128;
    u64 best[10];
#pragma unroll
    for (int i = 0; i < 10; ++i) best[i] = L[t1 * 10 + i];
#pragma unroll
    for (int i = 0; i < 10; ++i) {
      u64 key = L[t2 * 10 + i];
      if (key <= best[9]) break;   // lists sorted desc
      insert10(best, key);
    }
    const size_t base = (size_t)blockIdx.y * 10;
#pragma unroll
    for (int j = 0; j < 10; ++j)
      cand[(base + j) * MQ + qbase + t] = best[j];
  }
}

// ---------------- kernel 3: merge candidates, labels, mode ----------------
__global__ __launch_bounds__(256) void knn_finalize(
    const u64* __restrict__ cand, float* __restrict__ out, int nSlots)
{
  const int row = blockIdx.x * 256 + threadIdx.x;
  if (row >= MQ) return;
  u64 lst[10];
#pragma unroll
  for (int i = 0; i < 10; ++i) lst[i] = 0ull;
  for (int s2 = 0; s2 < nSlots; ++s2) {
    const u64 key = cand[(size_t)s2 * MQ + row];   // coalesced: stride-1 in row
    if (key > lst[9]) insert10(lst, key);
  }
  // labels = col/5000 ; mode with first-wins tie-break (matches argmax)
  int best = 0, bestc = 0;
#pragma unroll
  for (int cls = 0; cls < 10; ++cls) {
    int cnt = 0;
#pragma unroll
    for (int j = 0; j < 10; ++j) {
      const int col = ((int)(lst[j] & 0xFFFFull)) ^ 0xFFFF;
      cnt += (col / 5000 == cls) ? 1 : 0;
    }
    if (cnt > bestc) { bestc = cnt; best = cls; }
  }
  out[row] = (float)best;
}

extern "C" void kernel_launch(void* const* d_in, const int* in_sizes, int n_in,
                              void* d_out, int out_size, void* d_ws, size_t ws_size,
                              hipStream_t stream)
{
  const float* Q = (const float*)d_in[0];
  const float* R = (const float*)d_in[1];
  float* out = (float*)d_out;

  // workspace: [cand: NC*10*MQ u64][rsq: ND f32][qsq: MQ f32]; shrink NC if needed
  int NC = 196;                         // chunkCols = 256 -> 2 BN-steps/block
  const size_t perChunk  = (size_t)10 * MQ * sizeof(u64);
  const size_t fixedTail = (size_t)(ND + MQ) * sizeof(float);
  while (NC > 1 && (size_t)NC * perChunk + fixedTail > ws_size) --NC;
  int chunkCols = (((ND + NC - 1) / NC) + BN - 1) / BN * BN;
  NC = (ND + chunkCols - 1) / chunkCols;   // effective chunk count

  u64*   cand = (u64*)d_ws;
  float* rsq  = (float*)((char*)d_ws + (size_t)NC * perChunk);
  float* qsq  = rsq + ND;

  const int nrows = ND + MQ;
  sqnorm_kernel<<<(nrows + 3) / 4, 256, 0, stream>>>(Q, R, rsq, qsq);
  knn_gemm_topk<<<dim3(MQ / BM, NC), 256, 0, stream>>>(Q, R, qsq, rsq, cand, chunkCols);
  knn_finalize<<<MQ / 256, 256, 0, stream>>>(cand, out, NC * 10);
}

// Round 4
// 2478.071 us; speedup vs baseline: 1.1450x; 1.0432x over previous
//
#include <hip/hip_runtime.h>

typedef unsigned long long u64;
typedef unsigned int u32;

#define MQ 2048
#define ND 50000
#define DD 512

constexpr int BM = 128, BN = 128, KC = 16;
constexpr int QSTR = 132;                 // LDS row stride (dwords)
constexpr int GY   = 56;                  // col-chunk blocks: 56*896=50176 >= ND
constexpr int CHUNK = 896;                // cols per chunk (7 BN-steps)
constexpr int SH_BYTES = 64 * QSTR * 4;   // 33792 B union: {Qs+Rs | DS | lists}

__device__ __forceinline__ void insert10(u64 (&lst)[10], u64 key) {
  u64 cur = key;                          // lst sorted descending
#pragma unroll
  for (int p = 0; p < 10; ++p) {
    u64 a = lst[p];
    u64 mx = a > cur ? a : cur;
    cur    = a > cur ? cur : a;
    lst[p] = mx;
  }
}

__device__ __forceinline__ u32 mk_key(float d, bool valid) {
  u32 kb = __float_as_uint(d);
  kb ^= (kb & 0x80000000u) ? 0xFFFFFFFFu : 0x80000000u;  // order-preserving uint
  return valid ? kb : 0u;
}

// ---------------- kernel 1: squared norms ----------------
__global__ __launch_bounds__(256) void sqnorm_kernel(
    const float* __restrict__ Q, const float* __restrict__ R,
    float* __restrict__ rsq, float* __restrict__ qsq)
{
  int wid  = blockIdx.x * 4 + (threadIdx.x >> 6);
  int lane = threadIdx.x & 63;
  if (wid >= ND + MQ) return;
  const float* p = (wid < ND) ? (R + (size_t)wid * DD)
                              : (Q + (size_t)(wid - ND) * DD);
  float s = 0.f;
#pragma unroll
  for (int it = 0; it < 2; ++it) {
    float4 v = *reinterpret_cast<const float4*>(p + lane * 4 + it * 256);
    s += v.x * v.x + v.y * v.y + v.z * v.z + v.w * v.w;
  }
#pragma unroll
  for (int off = 32; off > 0; off >>= 1) s += __shfl_down(s, off, 64);
  if (lane == 0) {
    if (wid < ND) rsq[wid] = s;
    else          qsq[wid - ND] = s;
  }
}

// ------------- kernel 2: fused GEMM-distance + per-chunk top-10 -------------
__global__ __launch_bounds__(256, 4) void knn_gemm_topk(
    const float* __restrict__ Q, const float* __restrict__ R,
    const float* __restrict__ qsq, const float* __restrict__ rsq,
    u64* __restrict__ cand)
{
  __shared__ __align__(16) char shm[SH_BYTES];
  float (*Qs)[QSTR] = reinterpret_cast<float(*)[QSTR]>(shm);                 // [KC][QSTR]
  float (*Rs)[QSTR] = reinterpret_cast<float(*)[QSTR]>(shm + KC * QSTR * 4); // [KC][QSTR]
  u32* DS = reinterpret_cast<u32*>(shm);   // [64][QSTR] dist keys (post-K-loop)
  u64* L  = reinterpret_cast<u64*>(shm);   // epilogue lists

  const int t  = threadIdx.x;
  const int tx = t & 15;
  const int ty = t >> 4;
  const int qbase  = blockIdx.x * BM;
  const int cbase0 = blockIdx.y * CHUNK;

  u64 lst[10];
#pragma unroll
  for (int i = 0; i < 10; ++i) lst[i] = 0ull;

  // top-k ownership: bit0 = row half, bits1-6 = row-in-half, bit7 = col segment
  const int tkhalf = t & 1;
  const int tkr    = (t >> 1) & 63;
  const int tkc0   = (t >> 7) * 64;

  for (int s = 0; s < CHUNK / BN; ++s) {
    const int cbase = cbase0 + s * BN;

    float acc[8][8];
#pragma unroll
    for (int i = 0; i < 8; ++i)
#pragma unroll
      for (int j = 0; j < 8; ++j) acc[i][j] = 0.f;

    for (int k0 = 0; k0 < DD; k0 += KC) {
      // stage k-slices transposed; row-position XOR-swizzled by k-group
      // (write banks exactly 2-way = free; readers use same compile-time XOR)
#pragma unroll
      for (int i2 = 0; i2 < 2; ++i2) {
        const int idx = t + i2 * 256;
        const int r   = idx >> 2;        // 0..127
        const int kg  = idx & 3;         // k-group
        const int c4  = kg * 4;
        const int rsw = r ^ (kg << 2);
        const float4 qv = *reinterpret_cast<const float4*>(Q + (size_t)(qbase + r) * DD + k0 + c4);
        Qs[c4 + 0][rsw] = qv.x; Qs[c4 + 1][rsw] = qv.y;
        Qs[c4 + 2][rsw] = qv.z; Qs[c4 + 3][rsw] = qv.w;
        int rr = cbase + r; if (rr >= ND) rr = ND - 1;
        const float4 rv = *reinterpret_cast<const float4*>(R + (size_t)rr * DD + k0 + c4);
        Rs[c4 + 0][rsw] = rv.x; Rs[c4 + 1][rsw] = rv.y;
        Rs[c4 + 2][rsw] = rv.z; Rs[c4 + 3][rsw] = rv.w;
      }
      __syncthreads();
      // kk grouped by swizzle class so fragment addresses fold to immediates
#pragma unroll
      for (int sw4 = 0; sw4 < 4; ++sw4) {
        const int sw = sw4 << 2;
        const int a1 = (ty * 4) ^ sw;
        const int a2 = 64 + ((ty * 4) ^ sw);
        const int b1 = (tx * 4) ^ sw;
        const int b2 = 64 + ((tx * 4) ^ sw);
#pragma unroll
        for (int n = 0; n < 4; ++n) {
          const int kk = sw4 * 4 + n;
          float a[8], b[8];
          *reinterpret_cast<float4*>(&a[0]) = *reinterpret_cast<const float4*>(&Qs[kk][a1]);
          *reinterpret_cast<float4*>(&a[4]) = *reinterpret_cast<const float4*>(&Qs[kk][a2]);
          *reinterpret_cast<float4*>(&b[0]) = *reinterpret_cast<const float4*>(&Rs[kk][b1]);
          *reinterpret_cast<float4*>(&b[4]) = *reinterpret_cast<const float4*>(&Rs[kk][b2]);
#pragma unroll
          for (int i = 0; i < 8; ++i)
#pragma unroll
            for (int j = 0; j < 8; ++j) acc[i][j] = fmaf(a[i], b[j], acc[i][j]);
        }
      }
      __syncthreads();
    }

    // distance keys -> DS (uint4 = b128, phase-conflict-free); then topk scan
    const float4 rv0 = *reinterpret_cast<const float4*>(rsq + cbase + 4 * tx);
    const float4 rv1 = *reinterpret_cast<const float4*>(rsq + cbase + 64 + 4 * tx);
#pragma unroll
    for (int h = 0; h < 2; ++h) {
#pragma unroll
      for (int i2 = 0; i2 < 4; ++i2) {
        const int rloc = ty * 4 + i2;
        const float qs = qsq[qbase + 64 * h + rloc];
        const int cb0 = cbase + 4 * tx;
        const int cb1 = cb0 + 64;
        uint4 w0, w1;
        w0.x = mk_key(qs + rv0.x - 2.f * acc[h * 4 + i2][0], cb0 + 0 < ND);
        w0.y = mk_key(qs + rv0.y - 2.f * acc[h * 4 + i2][1], cb0 + 1 < ND);
        w0.z = mk_key(qs + rv0.z - 2.f * acc[h * 4 + i2][2], cb0 + 2 < ND);
        w0.w = mk_key(qs + rv0.w - 2.f * acc[h * 4 + i2][3], cb0 + 3 < ND);
        w1.x = mk_key(qs + rv1.x - 2.f * acc[h * 4 + i2][4], cb1 + 0 < ND);
        w1.y = mk_key(qs + rv1.y - 2.f * acc[h * 4 + i2][5], cb1 + 1 < ND);
        w1.z = mk_key(qs + rv1.z - 2.f * acc[h * 4 + i2][6], cb1 + 2 < ND);
        w1.w = mk_key(qs + rv1.w - 2.f * acc[h * 4 + i2][7], cb1 + 3 < ND);
        *reinterpret_cast<uint4*>(&DS[rloc * QSTR + 4 * tx])      = w0;
        *reinterpret_cast<uint4*>(&DS[rloc * QSTR + 64 + 4 * tx]) = w1;
      }
      __syncthreads();
      if (tkhalf == h) {
        const u32 m0 = 0xFFFFu - (u32)(cbase + tkc0);   // (col ^ 0xFFFF) base
#pragma unroll 4
        for (int cc = 0; cc < 32; ++cc) {
          const int c2 = (cc + tkr) & 31;               // rotated u64-pair index
          const u64 pr = *reinterpret_cast<const u64*>(&DS[tkr * QSTR + tkc0 + 2 * c2]);
          const u64 key0 = ((pr & 0xFFFFFFFFull) << 16) | (u64)(m0 - 2 * c2);
          const u64 key1 = ((pr >> 32) << 16)           | (u64)(m0 - 2 * c2 - 1);
          if (key0 > lst[9]) insert10(lst, key0);
          if (key1 > lst[9]) insert10(lst, key1);
        }
      }
      __syncthreads();
    }
  }

  // epilogue: merge the two col-segment lists per row; write 10 cand/row
#pragma unroll
  for (int i = 0; i < 10; ++i) L[t * 10 + i] = lst[i];
  __syncthreads();
  if (t < BM) {
    const int t1 = ((t & 63) << 1) | (t >> 6);
    const int t2 = t1 | 128;
    u64 best[10];
#pragma unroll
    for (int i = 0; i < 10; ++i) best[i] = L[t1 * 10 + i];
#pragma unroll
    for (int i = 0; i < 10; ++i) {
      u64 key = L[t2 * 10 + i];
      if (key <= best[9]) break;        // lists sorted desc
      insert10(best, key);
    }
    const size_t base = (size_t)blockIdx.y * 10;
#pragma unroll
    for (int j = 0; j < 10; ++j)
      cand[(base + j) * MQ + qbase + t] = best[j];
  }
}

// ---------------- kernel 3: merge candidates, labels, mode ----------------
__global__ __launch_bounds__(256) void knn_finalize(
    const u64* __restrict__ cand, float* __restrict__ out, int nSlots)
{
  __shared__ u64 ML[256][10];
  const int t   = threadIdx.x;
  const int row = blockIdx.x * 32 + (t >> 3);
  const int l8  = t & 7;
  u64 lst[10];
#pragma unroll
  for (int i = 0; i < 10; ++i) lst[i] = 0ull;
  for (int s2 = l8; s2 < nSlots; s2 += 8) {
    const u64 key = cand[(size_t)s2 * MQ + row];   // coalesced in row
    if (key > lst[9]) insert10(lst, key);
  }
#pragma unroll
  for (int i = 0; i < 10; ++i) ML[t][i] = lst[i];
  __syncthreads();
  if (l8 == 0) {
#pragma unroll
    for (int m = 1; m < 8; ++m) {
#pragma unroll
      for (int i = 0; i < 10; ++i) {
        const u64 key = ML[t + m][i];
        if (key <= lst[9]) break;
        insert10(lst, key);
      }
    }
    int best = 0, bestc = 0;
#pragma unroll
    for (int cls = 0; cls < 10; ++cls) {
      int cnt = 0;
#pragma unroll
      for (int j = 0; j < 10; ++j) {
        const int col = ((int)(lst[j] & 0xFFFFull)) ^ 0xFFFF;
        cnt += (col / 5000 == cls) ? 1 : 0;
      }
      if (cnt > bestc) { bestc = cnt; best = cls; }
    }
    out[row] = (float)best;
  }
}

extern "C" void kernel_launch(void* const* d_in, const int* in_sizes, int n_in,
                              void* d_out, int out_size, void* d_ws, size_t ws_size,
                              hipStream_t stream)
{
  const float* Q = (const float*)d_in[0];
  const float* R = (const float*)d_in[1];
  float* out = (float*)d_out;

  // ws layout: [cand: GY*10*MQ u64 = 9.2 MB][rsq: ND f32][qsq: MQ f32]
  // (ws_size proven >= 32 MB in round 2)
  u64*   cand = (u64*)d_ws;
  float* rsq  = (float*)((char*)d_ws + (size_t)GY * 10 * MQ * sizeof(u64));
  float* qsq  = rsq + ND;

  const int nrows = ND + MQ;
  sqnorm_kernel<<<(nrows + 3) / 4, 256, 0, stream>>>(Q, R, rsq, qsq);
  knn_gemm_topk<<<dim3(MQ / BM, GY), 256, 0, stream>>>(Q, R, qsq, rsq, cand);
  knn_finalize<<<MQ / 32, 256, 0, stream>>>(cand, out, GY * 10);
}

// Round 5
// 1358.231 us; speedup vs baseline: 2.0891x; 1.8245x over previous
//
#include <hip/hip_runtime.h>

typedef unsigned long long u64;
typedef unsigned int u32;
using bf16x8 = __attribute__((ext_vector_type(8))) __bf16;
using f32x16 = __attribute__((ext_vector_type(16))) float;

#define MQ 2048
#define ND 50000
#define DD 512

constexpr int NT     = (ND + 127) / 128;   // 391 col-tiles of 128
constexpr int NDPAD  = 50176;              // padded rsq allocation
constexpr int DSTR   = 132;                // DS row stride (dwords)
constexpr int SH_BYTES = 128 * DSTR * 4;   // 67584 B union: {Qh/Ql/Rh/Rl | DS | L}

__device__ __forceinline__ void insert10(u64 (&lst)[10], u64 key) {
  u64 cur = key;                           // lst sorted descending
#pragma unroll
  for (int p = 0; p < 10; ++p) {
    u64 a = lst[p];
    u64 mx = a > cur ? a : cur;
    cur    = a > cur ? cur : a;
    lst[p] = mx;
  }
}

__device__ __forceinline__ u32 bf_hi_rtn(float x) {   // bf16 round-to-nearest-even, as bits
  u32 b = __float_as_uint(x);
  return (b + 0x7FFFu + ((b >> 16) & 1u)) >> 16;
}

// ---------------- kernel 1: squared norms ----------------
__global__ __launch_bounds__(256) void sqnorm_kernel(
    const float* __restrict__ Q, const float* __restrict__ R,
    float* __restrict__ rsq, float* __restrict__ qsq)
{
  int wid  = blockIdx.x * 4 + (threadIdx.x >> 6);
  int lane = threadIdx.x & 63;
  if (wid >= ND + MQ) return;
  const float* p = (wid < ND) ? (R + (size_t)wid * DD)
                              : (Q + (size_t)(wid - ND) * DD);
  float s = 0.f;
#pragma unroll
  for (int it = 0; it < 2; ++it) {
    float4 v = *reinterpret_cast<const float4*>(p + lane * 4 + it * 256);
    s += v.x * v.x + v.y * v.y + v.z * v.z + v.w * v.w;
  }
#pragma unroll
  for (int off = 32; off > 0; off >>= 1) s += __shfl_down(s, off, 64);
  if (lane == 0) {
    if (wid < ND) rsq[wid] = s;
    else          qsq[wid - ND] = s;
  }
}

// ------- kernel 2: split-bf16 MFMA GEMM-distance + fused per-chunk top-10 -------
// Block: 128 q-rows x (tilesPerBlock * 128) cols. 4 waves, each owns 64x64
// (2x2 grid of 32x32x16 mfma frags). Split: q.r = Qh.Rh + Qh.Rl + Ql.Rh.
__global__ __launch_bounds__(256, 2) void knn_mfma_topk(
    const float* __restrict__ Q, const float* __restrict__ R,
    const float* __restrict__ qsq, const float* __restrict__ rsq,
    u64* __restrict__ cand, int tilesPerBlock)
{
  __shared__ __align__(16) char shm[SH_BYTES];
  __shared__ float qs_lds[128];
  ushort* Qh = (ushort*)shm;            // [128][64] bf16, k-swizzled
  ushort* Ql = Qh + 8192;
  ushort* Rh = Ql + 8192;
  ushort* Rl = Rh + 8192;
  u32* DS = (u32*)shm;                  // [128][DSTR] dist keys (post-K)
  u64* L  = (u64*)shm;                  // epilogue lists

  const int t    = threadIdx.x;
  const int lane = t & 63;
  const int l31  = lane & 31;
  const int lh   = (lane >> 5) & 1;     // lane half
  const int wq   = t >> 7;              // wave row-half (0..1)
  const int wc   = (t >> 6) & 1;        // wave col-half (0..1)
  const int qbase = blockIdx.x * 128;

  if (t < 128) qs_lds[t] = qsq[qbase + t];   // read in dist phase (post-barriers)

  u64 lst[10];
#pragma unroll
  for (int i = 0; i < 10; ++i) lst[i] = 0ull;

  const int tkrow = t >> 1;             // scan: row owned by this thread
  const int tkc0  = (t & 1) * 64;       // scan: 64-col half

  for (int ct = 0; ct < tilesPerBlock; ++ct) {
    const int tile = blockIdx.y * tilesPerBlock + ct;
    if (tile >= NT) break;
    const int cbase = tile * 128;

    f32x16 acc[2][2];
#pragma unroll
    for (int rg = 0; rg < 2; ++rg)
#pragma unroll
      for (int cg = 0; cg < 2; ++cg)
#pragma unroll
        for (int e = 0; e < 16; ++e) acc[rg][cg][e] = 0.f;

    for (int k0 = 0; k0 < DD; k0 += 64) {
      __syncthreads();   // prev mfma reads / prev scan done before overwrite
      // ---- stage Q k-slice: fp32 -> bf16 hi/lo, swizzled ----
#pragma unroll
      for (int i = 0; i < 8; ++i) {
        const int idx = t + i * 256;
        const int r   = idx >> 4;            // 0..127
        const int c4  = (idx & 15) * 4;      // k element 0..60
        const float4 v = *reinterpret_cast<const float4*>(Q + (size_t)(qbase + r) * DD + k0 + c4);
        const u32 h0 = bf_hi_rtn(v.x), h1 = bf_hi_rtn(v.y), h2 = bf_hi_rtn(v.z), h3 = bf_hi_rtn(v.w);
        const u32 g0 = bf_hi_rtn(v.x - __uint_as_float(h0 << 16));
        const u32 g1 = bf_hi_rtn(v.y - __uint_as_float(h1 << 16));
        const u32 g2 = bf_hi_rtn(v.z - __uint_as_float(h2 << 16));
        const u32 g3 = bf_hi_rtn(v.w - __uint_as_float(h3 << 16));
        const int kk = c4 ^ ((r & 7) << 3);  // XOR swizzle (element units)
        *reinterpret_cast<u64*>(&Qh[r * 64 + kk]) =
            (u64)h0 | ((u64)h1 << 16) | ((u64)h2 << 32) | ((u64)h3 << 48);
        *reinterpret_cast<u64*>(&Ql[r * 64 + kk]) =
            (u64)g0 | ((u64)g1 << 16) | ((u64)g2 << 32) | ((u64)g3 << 48);
      }
      // ---- stage R k-slice ----
#pragma unroll
      for (int i = 0; i < 8; ++i) {
        const int idx = t + i * 256;
        const int r   = idx >> 4;
        const int c4  = (idx & 15) * 4;
        int rr = cbase + r; if (rr >= ND) rr = ND - 1;
        const float4 v = *reinterpret_cast<const float4*>(R + (size_t)rr * DD + k0 + c4);
        const u32 h0 = bf_hi_rtn(v.x), h1 = bf_hi_rtn(v.y), h2 = bf_hi_rtn(v.z), h3 = bf_hi_rtn(v.w);
        const u32 g0 = bf_hi_rtn(v.x - __uint_as_float(h0 << 16));
        const u32 g1 = bf_hi_rtn(v.y - __uint_as_float(h1 << 16));
        const u32 g2 = bf_hi_rtn(v.z - __uint_as_float(h2 << 16));
        const u32 g3 = bf_hi_rtn(v.w - __uint_as_float(h3 << 16));
        const int kk = c4 ^ ((r & 7) << 3);
        *reinterpret_cast<u64*>(&Rh[r * 64 + kk]) =
            (u64)h0 | ((u64)h1 << 16) | ((u64)h2 << 32) | ((u64)h3 << 48);
        *reinterpret_cast<u64*>(&Rl[r * 64 + kk]) =
            (u64)g0 | ((u64)g1 << 16) | ((u64)g2 << 32) | ((u64)g3 << 48);
      }
      __syncthreads();
      // ---- mfma: 4 k16-substeps, 12 mfma each (3-term split x 2x2 frags) ----
#pragma unroll
      for (int ks = 0; ks < 4; ++ks) {
        const int kb = ks * 16 + (lh << 3);  // element base for this lane-half
        bf16x8 ah[2], al[2], bh[2], bl[2];
#pragma unroll
        for (int rg = 0; rg < 2; ++rg) {
          const int ra  = wq * 64 + rg * 32 + l31;
          const int off = ra * 64 + (kb ^ ((ra & 7) << 3));
          ah[rg] = *reinterpret_cast<const bf16x8*>(&Qh[off]);
          al[rg] = *reinterpret_cast<const bf16x8*>(&Ql[off]);
        }
#pragma unroll
        for (int cg = 0; cg < 2; ++cg) {
          const int rb  = wc * 64 + cg * 32 + l31;
          const int off = rb * 64 + (kb ^ ((rb & 7) << 3));
          bh[cg] = *reinterpret_cast<const bf16x8*>(&Rh[off]);
          bl[cg] = *reinterpret_cast<const bf16x8*>(&Rl[off]);
        }
#pragma unroll
        for (int rg = 0; rg < 2; ++rg)
#pragma unroll
          for (int cg = 0; cg < 2; ++cg) {
            acc[rg][cg] = __builtin_amdgcn_mfma_f32_32x32x16_bf16(ah[rg], bh[cg], acc[rg][cg], 0, 0, 0);
            acc[rg][cg] = __builtin_amdgcn_mfma_f32_32x32x16_bf16(ah[rg], bl[cg], acc[rg][cg], 0, 0, 0);
            acc[rg][cg] = __builtin_amdgcn_mfma_f32_32x32x16_bf16(al[rg], bh[cg], acc[rg][cg], 0, 0, 0);
          }
      }
    }
    __syncthreads();   // all LDS frag reads done before DS overwrite

    // ---- distance keys -> DS (C/D layout: col=lane&31, row=(e&3)+8*(e>>2)+4*lh) ----
    const float rs0 = rsq[cbase + wc * 64 + l31];
    const float rs1 = rsq[cbase + wc * 64 + 32 + l31];
#pragma unroll
    for (int rg = 0; rg < 2; ++rg)
#pragma unroll
      for (int cg = 0; cg < 2; ++cg) {
        const float rsv = cg ? rs1 : rs0;
        const int cl    = wc * 64 + cg * 32 + l31;
        const bool valid = (cbase + cl) < ND;
#pragma unroll
        for (int e = 0; e < 16; ++e) {
          const int rl = wq * 64 + rg * 32 + (e & 3) + ((e >> 2) << 3) + (lh << 2);
          const float d = qs_lds[rl] + rsv - 2.0f * acc[rg][cg][e];
          u32 kb2 = __float_as_uint(d);
          kb2 ^= (kb2 & 0x80000000u) ? 0xFFFFFFFFu : 0x80000000u;  // order-preserving
          DS[rl * DSTR + cl] = valid ? kb2 : 0u;
        }
      }
    __syncthreads();

    // ---- scan: thread owns (row, 64-col half); rotated u64-pair reads ----
    {
      const u32 m0 = 0xFFFFu - (u32)(cbase + tkc0);   // (col ^ 0xFFFF) base
#pragma unroll 4
      for (int cc = 0; cc < 32; ++cc) {
        const int c2 = (cc + tkrow) & 31;
        const u64 pr = *reinterpret_cast<const u64*>(&DS[tkrow * DSTR + tkc0 + 2 * c2]);
        const u64 key0 = ((pr & 0xFFFFFFFFull) << 16) | (u64)(m0 - 2 * c2);
        const u64 key1 = ((pr >> 32) << 16)           | (u64)(m0 - 2 * c2 - 1);
        if (key0 > lst[9]) insert10(lst, key0);
        if (key1 > lst[9]) insert10(lst, key1);
      }
    }
    __syncthreads();   // before next tile's staging overwrites the union
  }

  // ---- epilogue: merge the two col-half lists per row; write 10 cand/row ----
#pragma unroll
  for (int i = 0; i < 10; ++i) L[t * 10 + i] = lst[i];
  __syncthreads();
  if (t < 128) {
    u64 best[10];
#pragma unroll
    for (int i = 0; i < 10; ++i) best[i] = L[(2 * t) * 10 + i];
#pragma unroll
    for (int i = 0; i < 10; ++i) {
      u64 key = L[(2 * t + 1) * 10 + i];
      if (key <= best[9]) break;        // lists sorted desc
      insert10(best, key);
    }
    const size_t base = (size_t)blockIdx.y * 10;
#pragma unroll
    for (int j = 0; j < 10; ++j)
      cand[(base + j) * MQ + qbase + t] = best[j];
  }
}

// ---------------- kernel 3: merge candidates, labels, mode ----------------
__global__ __launch_bounds__(256) void knn_finalize(
    const u64* __restrict__ cand, float* __restrict__ out, int nSlots)
{
  __shared__ u64 ML[256][10];
  const int t   = threadIdx.x;
  const int row = blockIdx.x * 32 + (t >> 3);
  const int l8  = t & 7;
  u64 lst[10];
#pragma unroll
  for (int i = 0; i < 10; ++i) lst[i] = 0ull;
  for (int s2 = l8; s2 < nSlots; s2 += 8) {
    const u64 key = cand[(size_t)s2 * MQ + row];   // coalesced in row
    if (key > lst[9]) insert10(lst, key);
  }
#pragma unroll
  for (int i = 0; i < 10; ++i) ML[t][i] = lst[i];
  __syncthreads();
  if (l8 == 0) {
#pragma unroll
    for (int m = 1; m < 8; ++m) {
#pragma unroll
      for (int i = 0; i < 10; ++i) {
        const u64 key = ML[t + m][i];
        if (key <= lst[9]) break;
        insert10(lst, key);
      }
    }
    int best = 0, bestc = 0;
#pragma unroll
    for (int cls = 0; cls < 10; ++cls) {
      int cnt = 0;
#pragma unroll
      for (int j = 0; j < 10; ++j) {
        const int col = ((int)(lst[j] & 0xFFFFull)) ^ 0xFFFF;
        cnt += (col / 5000 == cls) ? 1 : 0;
      }
      if (cnt > bestc) { bestc = cnt; best = cls; }
    }
    out[row] = (float)best;
  }
}

extern "C" void kernel_launch(void* const* d_in, const int* in_sizes, int n_in,
                              void* d_out, int out_size, void* d_ws, size_t ws_size,
                              hipStream_t stream)
{
  const float* Q = (const float*)d_in[0];
  const float* R = (const float*)d_in[1];
  float* out = (float*)d_out;

  // pick tiles/block so cand fits ws: tpb=4 -> 98 chunks (16.3 MB); 8 -> 8.2 MB (proven safe)
  int tpb = 4;
  auto need = [&](int T) -> size_t {
    int gy = (NT + T - 1) / T;
    return (size_t)gy * 10 * MQ * sizeof(u64) + (size_t)(NDPAD + MQ) * sizeof(float);
  };
  while (tpb < 64 && need(tpb) > ws_size) tpb *= 2;
  const int gy = (NT + tpb - 1) / tpb;

  u64*   cand = (u64*)d_ws;
  float* rsq  = (float*)((char*)d_ws + (size_t)gy * 10 * MQ * sizeof(u64));
  float* qsq  = rsq + NDPAD;

  sqnorm_kernel<<<(ND + MQ + 3) / 4, 256, 0, stream>>>(Q, R, rsq, qsq);
  knn_mfma_topk<<<dim3(MQ / 128, gy), 256, 0, stream>>>(Q, R, qsq, rsq, cand, tpb);
  knn_finalize<<<MQ / 32, 256, 0, stream>>>(cand, out, gy * 10);
}

// Round 6
// 838.356 us; speedup vs baseline: 3.3846x; 1.6201x over previous
//
#include <hip/hip_runtime.h>

typedef unsigned long long u64;
typedef unsigned int u32;
typedef unsigned short u16;
using bf16x8 = __attribute__((ext_vector_type(8))) __bf16;
using f32x16 = __attribute__((ext_vector_type(16))) float;

#define MQ 2048
#define ND 50000
#define DD 512

constexpr int NT    = 391;                // col-tiles of 128 (391*128 = 50048)
constexpr int NDPAD = NT * 128;           // padded R rows for bf16 arrays
constexpr int TPB   = 4;                  // tiles per block (main path)
constexpr int GYM   = (NT + TPB - 1) / TPB;   // 98 col-chunks
constexpr int DSTR  = 132;                // DS row stride (dwords)
constexpr int SHB   = 128 * DSTR * 4;     // 67584 B union {4 bf16 arrays | DS | L}

__device__ __forceinline__ void insert10(u64 (&lst)[10], u64 key) {
  u64 cur = key;                          // lst sorted descending
#pragma unroll
  for (int p = 0; p < 10; ++p) {
    u64 a = lst[p];
    u64 mx = a > cur ? a : cur;
    cur    = a > cur ? cur : a;
    lst[p] = mx;
  }
}

__device__ __forceinline__ u32 bf_hi_rtn(float x) {   // bf16 RTNE, as bits
  u32 b = __float_as_uint(x);
  return (b + 0x7FFFu + ((b >> 16) & 1u)) >> 16;
}

__device__ __forceinline__ void gl_lds16(const void* g, void* l) {
  __builtin_amdgcn_global_load_lds(
      (const __attribute__((address_space(1))) u32*)g,
      (__attribute__((address_space(3))) u32*)l, 16, 0, 0);
}

// ---- kernel 1 (main path): fp32 -> bf16 hi/lo split + row sq-norms ----
__global__ __launch_bounds__(256) void convert_kernel(
    const float* __restrict__ Q, const float* __restrict__ R,
    u16* __restrict__ Qh, u16* __restrict__ Ql,
    u16* __restrict__ Rh, u16* __restrict__ Rl,
    float* __restrict__ rsq, float* __restrict__ qsq)
{
  const int wid  = blockIdx.x * 4 + (threadIdx.x >> 6);
  const int lane = threadIdx.x & 63;
  if (wid >= ND + MQ) return;
  const bool isR = wid < ND;
  const size_t row = isR ? (size_t)wid : (size_t)(wid - ND);
  const float* src = (isR ? R : Q) + row * DD;
  u16* hD = (isR ? Rh : Qh) + row * DD;
  u16* lD = (isR ? Rl : Ql) + row * DD;

  float s = 0.f;
#pragma unroll
  for (int it = 0; it < 2; ++it) {
    const int e = lane * 4 + it * 256;
    const float4 v = *reinterpret_cast<const float4*>(src + e);
    s += v.x * v.x + v.y * v.y + v.z * v.z + v.w * v.w;
    const u32 h0 = bf_hi_rtn(v.x), h1 = bf_hi_rtn(v.y), h2 = bf_hi_rtn(v.z), h3 = bf_hi_rtn(v.w);
    const u32 g0 = bf_hi_rtn(v.x - __uint_as_float(h0 << 16));
    const u32 g1 = bf_hi_rtn(v.y - __uint_as_float(h1 << 16));
    const u32 g2 = bf_hi_rtn(v.z - __uint_as_float(h2 << 16));
    const u32 g3 = bf_hi_rtn(v.w - __uint_as_float(h3 << 16));
    *reinterpret_cast<u64*>(hD + e) = (u64)h0 | ((u64)h1 << 16) | ((u64)h2 << 32) | ((u64)h3 << 48);
    *reinterpret_cast<u64*>(lD + e) = (u64)g0 | ((u64)g1 << 16) | ((u64)g2 << 32) | ((u64)g3 << 48);
  }
#pragma unroll
  for (int off = 32; off > 0; off >>= 1) s += __shfl_down(s, off, 64);
  if (lane == 0) {
    if (isR) rsq[row] = s;
    else     qsq[row] = s;
  }
}

// ---- kernel 2 (main path): MFMA GEMM-distance from pre-split bf16 + top-10 ----
// 128x128 tile, BK=64, single-buffered LDS via global_load_lds (m97 structure),
// 2 blocks/CU. LDS linear; frag XOR-swizzle folded into per-lane GLOBAL src addr.
__global__ __launch_bounds__(256, 2) void knn_mfma_topk(
    const u16* __restrict__ Qhg, const u16* __restrict__ Qlg,
    const u16* __restrict__ Rhg, const u16* __restrict__ Rlg,
    const float* __restrict__ qsq, const float* __restrict__ rsq,
    u64* __restrict__ cand)
{
  __shared__ __align__(16) char shm[SHB];
  __shared__ float qs_lds[128];
  u16* Qh_l = (u16*)shm;                // [128 rows][64 k] bf16, chunk-swizzled
  u16* Ql_l = Qh_l + 8192;
  u16* Rh_l = Ql_l + 8192;
  u16* Rl_l = Rh_l + 8192;
  u32* DS = (u32*)shm;                  // [128][DSTR] dist keys (post-K)
  u64* L  = (u64*)shm;                  // epilogue lists

  const int t    = threadIdx.x;
  const int lane = t & 63;
  const int l31  = lane & 31;
  const int lh   = (lane >> 5) & 1;
  const int w    = t >> 6;              // wave id
  const int wq   = t >> 7;              // wave row-half
  const int wc   = (t >> 6) & 1;        // wave col-half
  const int qbase = blockIdx.x * 128;

  if (t < 128) qs_lds[t] = qsq[qbase + t];

  // staging constants: LDS-linear dest; swizzle folded into global src.
  // round r of wave w covers rows w*32+8r+(lane>>3), chunk lane&7 holds
  // global chunk (lane&7)^(lane>>3)  (row&7 == lane>>3 for these rows).
  const int sBR  = w * 32 + (lane >> 3);               // staging base row
  const int sCH  = (((lane & 7) ^ (lane >> 3)) << 3);  // swizzled k-offset (elements)

  u64 lst[10];
#pragma unroll
  for (int i = 0; i < 10; ++i) lst[i] = 0ull;

  const int tkrow = t >> 1;             // scan: owned row
  const int tkc0  = (t & 1) * 64;       // scan: 64-col half

  for (int ct = 0; ct < TPB; ++ct) {
    const int tile = blockIdx.y * TPB + ct;
    if (tile >= NT) break;
    const int cbase = tile * 128;

    f32x16 acc[2][2];
#pragma unroll
    for (int rg = 0; rg < 2; ++rg)
#pragma unroll
      for (int cg = 0; cg < 2; ++cg)
#pragma unroll
        for (int e = 0; e < 16; ++e) acc[rg][cg][e] = 0.f;

    const size_t qrow0 = (size_t)(qbase + sBR) * DD + sCH;
    const size_t rrow0 = (size_t)(cbase + sBR) * DD + sCH;

    for (int kt = 0; kt < 8; ++kt) {
      const int k0 = kt * 64;
      // ---- stage 64 KB: Qh/Ql/Rh/Rl [128][64] via global_load_lds x16 ----
#pragma unroll
      for (int r = 0; r < 4; ++r) {
        const size_t qo = qrow0 + (size_t)r * (8 * DD) + k0;
        const size_t ro = rrow0 + (size_t)r * (8 * DD) + k0;
        u16* dst = Qh_l + (w * 4 + r) * 512;   // 1 KB per wave-round, uniform
        gl_lds16(Qhg + qo, dst);
        gl_lds16(Qlg + qo, dst + 8192);
        gl_lds16(Rhg + ro, dst + 16384);
        gl_lds16(Rlg + ro, dst + 24576);
      }
      __syncthreads();                          // drains vmcnt -> LDS ready
      // ---- 4 k16-substeps x 12 mfma (3-term split x 2x2 frags) ----
#pragma unroll
      for (int ks = 0; ks < 4; ++ks) {
        const int gch = ks * 2 + lh;            // global k-chunk 0..7
        bf16x8 ah[2], al[2], bh[2], bl[2];
#pragma unroll
        for (int rg = 0; rg < 2; ++rg) {
          const int ra  = wq * 64 + rg * 32 + l31;
          const int off = ra * 64 + ((gch ^ (ra & 7)) << 3);
          ah[rg] = *reinterpret_cast<const bf16x8*>(Qh_l + off);
          al[rg] = *reinterpret_cast<const bf16x8*>(Ql_l + off);
        }
#pragma unroll
        for (int cg = 0; cg < 2; ++cg) {
          const int rb  = wc * 64 + cg * 32 + l31;
          const int off = rb * 64 + ((gch ^ (rb & 7)) << 3);
          bh[cg] = *reinterpret_cast<const bf16x8*>(Rh_l + off);
          bl[cg] = *reinterpret_cast<const bf16x8*>(Rl_l + off);
        }
#pragma unroll
        for (int rg = 0; rg < 2; ++rg)
#pragma unroll
          for (int cg = 0; cg < 2; ++cg) {
            acc[rg][cg] = __builtin_amdgcn_mfma_f32_32x32x16_bf16(ah[rg], bh[cg], acc[rg][cg], 0, 0, 0);
            acc[rg][cg] = __builtin_amdgcn_mfma_f32_32x32x16_bf16(ah[rg], bl[cg], acc[rg][cg], 0, 0, 0);
            acc[rg][cg] = __builtin_amdgcn_mfma_f32_32x32x16_bf16(al[rg], bh[cg], acc[rg][cg], 0, 0, 0);
          }
      }
      __syncthreads();                          // frag reads done before restage
    }

    // ---- distance keys -> DS (C/D: col=lane&31, row=(e&3)+8*(e>>2)+4*lh) ----
    const float rs0 = rsq[cbase + wc * 64 + l31];
    const float rs1 = rsq[cbase + wc * 64 + 32 + l31];
#pragma unroll
    for (int rg = 0; rg < 2; ++rg)
#pragma unroll
      for (int cg = 0; cg < 2; ++cg) {
        const float rsv = cg ? rs1 : rs0;
        const int cl    = wc * 64 + cg * 32 + l31;
        const bool valid = (cbase + cl) < ND;
#pragma unroll
        for (int e = 0; e < 16; ++e) {
          const int rl = wq * 64 + rg * 32 + (e & 3) + ((e >> 2) << 3) + (lh << 2);
          const float d = qs_lds[rl] + rsv - 2.0f * acc[rg][cg][e];
          u32 kb2 = __float_as_uint(d);
          kb2 ^= (kb2 & 0x80000000u) ? 0xFFFFFFFFu : 0x80000000u;
          DS[rl * DSTR + cl] = valid ? kb2 : 0u;
        }
      }
    __syncthreads();

    // ---- scan: thread owns (row, 64-col half); rotated u64-pair reads ----
    {
      const u32 m0 = 0xFFFFu - (u32)(cbase + tkc0);
#pragma unroll 4
      for (int cc = 0; cc < 32; ++cc) {
        const int c2 = (cc + tkrow) & 31;
        const u64 pr = *reinterpret_cast<const u64*>(&DS[tkrow * DSTR + tkc0 + 2 * c2]);
        const u64 key0 = ((pr & 0xFFFFFFFFull) << 16) | (u64)(m0 - 2 * c2);
        const u64 key1 = ((pr >> 32) << 16)           | (u64)(m0 - 2 * c2 - 1);
        if (key0 > lst[9]) insert10(lst, key0);
        if (key1 > lst[9]) insert10(lst, key1);
      }
    }
    __syncthreads();                            // before next tile's staging
  }

  // ---- epilogue: merge the two col-half lists per row; write 10 cand/row ----
#pragma unroll
  for (int i = 0; i < 10; ++i) L[t * 10 + i] = lst[i];
  __syncthreads();
  if (t < 128) {
    u64 best[10];
#pragma unroll
    for (int i = 0; i < 10; ++i) best[i] = L[(2 * t) * 10 + i];
#pragma unroll
    for (int i = 0; i < 10; ++i) {
      u64 key = L[(2 * t + 1) * 10 + i];
      if (key <= best[9]) break;
      insert10(best, key);
    }
    const size_t base = (size_t)blockIdx.y * 10;
#pragma unroll
    for (int j = 0; j < 10; ++j)
      cand[(base + j) * MQ + qbase + t] = best[j];
  }
}

// ---------------- kernel 3: merge candidates, labels, mode ----------------
__global__ __launch_bounds__(256) void knn_finalize(
    const u64* __restrict__ cand, float* __restrict__ out, int nSlots)
{
  __shared__ u64 ML[256][10];
  const int t   = threadIdx.x;
  const int row = blockIdx.x * 32 + (t >> 3);
  const int l8  = t & 7;
  u64 lst[10];
#pragma unroll
  for (int i = 0; i < 10; ++i) lst[i] = 0ull;
  for (int s2 = l8; s2 < nSlots; s2 += 8) {
    const u64 key = cand[(size_t)s2 * MQ + row];
    if (key > lst[9]) insert10(lst, key);
  }
#pragma unroll
  for (int i = 0; i < 10; ++i) ML[t][i] = lst[i];
  __syncthreads();
  if (l8 == 0) {
#pragma unroll
    for (int m = 1; m < 8; ++m) {
#pragma unroll
      for (int i = 0; i < 10; ++i) {
        const u64 key = ML[t + m][i];
        if (key <= lst[9]) break;
        insert10(lst, key);
      }
    }
    int best = 0, bestc = 0;
#pragma unroll
    for (int cls = 0; cls < 10; ++cls) {
      int cnt = 0;
#pragma unroll
      for (int j = 0; j < 10; ++j) {
        const int col = ((int)(lst[j] & 0xFFFFull)) ^ 0xFFFF;
        cnt += (col / 5000 == cls) ? 1 : 0;
      }
      if (cnt > bestc) { bestc = cnt; best = cls; }
    }
    out[row] = (float)best;
  }
}

// ================= fallback path (round-5, proven): used if ws too small ======
__global__ __launch_bounds__(256) void sqnorm_kernel(
    const float* __restrict__ Q, const float* __restrict__ R,
    float* __restrict__ rsq, float* __restrict__ qsq)
{
  int wid  = blockIdx.x * 4 + (threadIdx.x >> 6);
  int lane = threadIdx.x & 63;
  if (wid >= ND + MQ) return;
  const float* p = (wid < ND) ? (R + (size_t)wid * DD)
                              : (Q + (size_t)(wid - ND) * DD);
  float s = 0.f;
#pragma unroll
  for (int it = 0; it < 2; ++it) {
    float4 v = *reinterpret_cast<const float4*>(p + lane * 4 + it * 256);
    s += v.x * v.x + v.y * v.y + v.z * v.z + v.w * v.w;
  }
#pragma unroll
  for (int off = 32; off > 0; off >>= 1) s += __shfl_down(s, off, 64);
  if (lane == 0) {
    if (wid < ND) rsq[wid] = s;
    else          qsq[wid - ND] = s;
  }
}

__global__ __launch_bounds__(256, 2) void knn_mfma_topk_fb(
    const float* __restrict__ Q, const float* __restrict__ R,
    const float* __restrict__ qsq, const float* __restrict__ rsq,
    u64* __restrict__ cand, int tilesPerBlock)
{
  __shared__ __align__(16) char shm[SHB];
  __shared__ float qs_lds[128];
  u16* Qh = (u16*)shm;
  u16* Ql = Qh + 8192;
  u16* Rh = Ql + 8192;
  u16* Rl = Rh + 8192;
  u32* DS = (u32*)shm;
  u64* L  = (u64*)shm;

  const int t    = threadIdx.x;
  const int lane = t & 63;
  const int l31  = lane & 31;
  const int lh   = (lane >> 5) & 1;
  const int wq   = t >> 7;
  const int wc   = (t >> 6) & 1;
  const int qbase = blockIdx.x * 128;

  if (t < 128) qs_lds[t] = qsq[qbase + t];

  u64 lst[10];
#pragma unroll
  for (int i = 0; i < 10; ++i) lst[i] = 0ull;

  const int tkrow = t >> 1;
  const int tkc0  = (t & 1) * 64;

  for (int ct = 0; ct < tilesPerBlock; ++ct) {
    const int tile = blockIdx.y * tilesPerBlock + ct;
    if (tile >= NT) break;
    const int cbase = tile * 128;

    f32x16 acc[2][2];
#pragma unroll
    for (int rg = 0; rg < 2; ++rg)
#pragma unroll
      for (int cg = 0; cg < 2; ++cg)
#pragma unroll
        for (int e = 0; e < 16; ++e) acc[rg][cg][e] = 0.f;

    for (int k0 = 0; k0 < DD; k0 += 64) {
      __syncthreads();
#pragma unroll
      for (int i = 0; i < 8; ++i) {
        const int idx = t + i * 256;
        const int r   = idx >> 4;
        const int c4  = (idx & 15) * 4;
        const float4 v = *reinterpret_cast<const float4*>(Q + (size_t)(qbase + r) * DD + k0 + c4);
        const u32 h0 = bf_hi_rtn(v.x), h1 = bf_hi_rtn(v.y), h2 = bf_hi_rtn(v.z), h3 = bf_hi_rtn(v.w);
        const u32 g0 = bf_hi_rtn(v.x - __uint_as_float(h0 << 16));
        const u32 g1 = bf_hi_rtn(v.y - __uint_as_float(h1 << 16));
        const u32 g2 = bf_hi_rtn(v.z - __uint_as_float(h2 << 16));
        const u32 g3 = bf_hi_rtn(v.w - __uint_as_float(h3 << 16));
        const int kk = c4 ^ ((r & 7) << 3);
        *reinterpret_cast<u64*>(&Qh[r * 64 + kk]) = (u64)h0 | ((u64)h1 << 16) | ((u64)h2 << 32) | ((u64)h3 << 48);
        *reinterpret_cast<u64*>(&Ql[r * 64 + kk]) = (u64)g0 | ((u64)g1 << 16) | ((u64)g2 << 32) | ((u64)g3 << 48);
      }
#pragma unroll
      for (int i = 0; i < 8; ++i) {
        const int idx = t + i * 256;
        const int r   = idx >> 4;
        const int c4  = (idx & 15) * 4;
        int rr = cbase + r; if (rr >= ND) rr = ND - 1;
        const float4 v = *reinterpret_cast<const float4*>(R + (size_t)rr * DD + k0 + c4);
        const u32 h0 = bf_hi_rtn(v.x), h1 = bf_hi_rtn(v.y), h2 = bf_hi_rtn(v.z), h3 = bf_hi_rtn(v.w);
        const u32 g0 = bf_hi_rtn(v.x - __uint_as_float(h0 << 16));
        const u32 g1 = bf_hi_rtn(v.y - __uint_as_float(h1 << 16));
        const u32 g2 = bf_hi_rtn(v.z - __uint_as_float(h2 << 16));
        const u32 g3 = bf_hi_rtn(v.w - __uint_as_float(h3 << 16));
        const int kk = c4 ^ ((r & 7) << 3);
        *reinterpret_cast<u64*>(&Rh[r * 64 + kk]) = (u64)h0 | ((u64)h1 << 16) | ((u64)h2 << 32) | ((u64)h3 << 48);
        *reinterpret_cast<u64*>(&Rl[r * 64 + kk]) = (u64)g0 | ((u64)g1 << 16) | ((u64)g2 << 32) | ((u64)g3 << 48);
      }
      __syncthreads();
#pragma unroll
      for (int ks = 0; ks < 4; ++ks) {
        const int kb = ks * 16 + (lh << 3);
        bf16x8 ah[2], al[2], bh[2], bl[2];
#pragma unroll
        for (int rg = 0; rg < 2; ++rg) {
          const int ra  = wq * 64 + rg * 32 + l31;
          const int off = ra * 64 + (kb ^ ((ra & 7) << 3));
          ah[rg] = *reinterpret_cast<const bf16x8*>(&Qh[off]);
          al[rg] = *reinterpret_cast<const bf16x8*>(&Ql[off]);
        }
#pragma unroll
        for (int cg = 0; cg < 2; ++cg) {
          const int rb  = wc * 64 + cg * 32 + l31;
          const int off = rb * 64 + (kb ^ ((rb & 7) << 3));
          bh[cg] = *reinterpret_cast<const bf16x8*>(&Rh[off]);
          bl[cg] = *reinterpret_cast<const bf16x8*>(&Rl[off]);
        }
#pragma unroll
        for (int rg = 0; rg < 2; ++rg)
#pragma unroll
          for (int cg = 0; cg < 2; ++cg) {
            acc[rg][cg] = __builtin_amdgcn_mfma_f32_32x32x16_bf16(ah[rg], bh[cg], acc[rg][cg], 0, 0, 0);
            acc[rg][cg] = __builtin_amdgcn_mfma_f32_32x32x16_bf16(ah[rg], bl[cg], acc[rg][cg], 0, 0, 0);
            acc[rg][cg] = __builtin_amdgcn_mfma_f32_32x32x16_bf16(al[rg], bh[cg], acc[rg][cg], 0, 0, 0);
          }
      }
    }
    __syncthreads();

    const float rs0 = rsq[cbase + wc * 64 + l31];
    const float rs1 = rsq[cbase + wc * 64 + 32 + l31];
#pragma unroll
    for (int rg = 0; rg < 2; ++rg)
#pragma unroll
      for (int cg = 0; cg < 2; ++cg) {
        const float rsv = cg ? rs1 : rs0;
        const int cl    = wc * 64 + cg * 32 + l31;
        const bool valid = (cbase + cl) < ND;
#pragma unroll
        for (int e = 0; e < 16; ++e) {
          const int rl = wq * 64 + rg * 32 + (e & 3) + ((e >> 2) << 3) + (lh << 2);
          const float d = qs_lds[rl] + rsv - 2.0f * acc[rg][cg][e];
          u32 kb2 = __float_as_uint(d);
          kb2 ^= (kb2 & 0x80000000u) ? 0xFFFFFFFFu : 0x80000000u;
          DS[rl * DSTR + cl] = valid ? kb2 : 0u;
        }
      }
    __syncthreads();
    {
      const u32 m0 = 0xFFFFu - (u32)(cbase + tkc0);
#pragma unroll 4
      for (int cc = 0; cc < 32; ++cc) {
        const int c2 = (cc + tkrow) & 31;
        const u64 pr = *reinterpret_cast<const u64*>(&DS[tkrow * DSTR + tkc0 + 2 * c2]);
        const u64 key0 = ((pr & 0xFFFFFFFFull) << 16) | (u64)(m0 - 2 * c2);
        const u64 key1 = ((pr >> 32) << 16)           | (u64)(m0 - 2 * c2 - 1);
        if (key0 > lst[9]) insert10(lst, key0);
        if (key1 > lst[9]) insert10(lst, key1);
      }
    }
    __syncthreads();
  }

#pragma unroll
  for (int i = 0; i < 10; ++i) L[t * 10 + i] = lst[i];
  __syncthreads();
  if (t < 128) {
    u64 best[10];
#pragma unroll
    for (int i = 0; i < 10; ++i) best[i] = L[(2 * t) * 10 + i];
#pragma unroll
    for (int i = 0; i < 10; ++i) {
      u64 key = L[(2 * t + 1) * 10 + i];
      if (key <= best[9]) break;
      insert10(best, key);
    }
    const size_t base = (size_t)blockIdx.y * 10;
#pragma unroll
    for (int j = 0; j < 10; ++j)
      cand[(base + j) * MQ + qbase + t] = best[j];
  }
}

extern "C" void kernel_launch(void* const* d_in, const int* in_sizes, int n_in,
                              void* d_out, int out_size, void* d_ws, size_t ws_size,
                              hipStream_t stream)
{
  const float* Q = (const float*)d_in[0];
  const float* R = (const float*)d_in[1];
  float* out = (float*)d_out;

  // main-path ws layout
  char* p = (char*)d_ws;
  u16* Qh = (u16*)p;                          p += (size_t)MQ * DD * 2;
  u16* Ql = (u16*)p;                          p += (size_t)MQ * DD * 2;
  u16* Rh = (u16*)p;                          p += (size_t)NDPAD * DD * 2;
  u16* Rl = (u16*)p;                          p += (size_t)NDPAD * DD * 2;
  float* rsq = (float*)p;                     p += (size_t)NDPAD * 4;
  float* qsq = (float*)p;                     p += (size_t)MQ * 4;
  u64* cand = (u64*)p;                        p += (size_t)GYM * 10 * MQ * 8;
  const size_t need = (size_t)(p - (char*)d_ws);

  if (need <= ws_size) {
    convert_kernel<<<(ND + MQ + 3) / 4, 256, 0, stream>>>(Q, R, Qh, Ql, Rh, Rl, rsq, qsq);
    knn_mfma_topk<<<dim3(MQ / 128, GYM), 256, 0, stream>>>(Qh, Ql, Rh, Rl, qsq, rsq, cand);
    knn_finalize<<<MQ / 32, 256, 0, stream>>>(cand, out, GYM * 10);
  } else {
    // round-5 fallback: on-the-fly conversion, adaptive chunk count
    int tpb = 4;
    auto need_fb = [&](int T) -> size_t {
      int gy = (NT + T - 1) / T;
      return (size_t)gy * 10 * MQ * sizeof(u64) + (size_t)(NDPAD + MQ) * sizeof(float);
    };
    while (tpb < 64 && need_fb(tpb) > ws_size) tpb *= 2;
    const int gy = (NT + tpb - 1) / tpb;
    u64*   candf = (u64*)d_ws;
    float* rsqf  = (float*)((char*)d_ws + (size_t)gy * 10 * MQ * sizeof(u64));
    float* qsqf  = rsqf + NDPAD;
    sqnorm_kernel<<<(ND + MQ + 3) / 4, 256, 0, stream>>>(Q, R, rsqf, qsqf);
    knn_mfma_topk_fb<<<dim3(MQ / 128, gy), 256, 0, stream>>>(Q, R, qsqf, rsqf, candf, tpb);
    knn_finalize<<<MQ / 32, 256, 0, stream>>>(candf, out, gy * 10);
  }
}